// Round 5
// baseline (201.424 us; speedup 1.0000x reference)
//
#include <hip/hip_runtime.h>

#define NS 65536
#define DD 32
#define RR 128
#define SPT 16                    // samples per tile
#define TPB 8                     // tiles per block (grid-stride: params staged once)
#define NBLK (NS / (SPT * TPB))   // 512 blocks = 2 per CU
#define TSTR 132                  // reduce-tile row stride: 528 B = 33*16 (b128-aligned, conflict-free)

// Block = 128 threads = 2 waves; thread t == rule. Params (w, naw, ck) staged in LDS
// once per block with rotated-chunk layout [r][(c+r)&7] (stride 32 floats, 16B-aligned,
// b128 reads hit the same 8-lane/bank-quad pattern as stride-1 => ~12cyc, no conflicts).
// Per d-chunk: 3 ds_read_b128 amortized over 16 samples => DS:VALU ~= 0.18/wave.
// X rows are uniform-address scalar loads (SMEM pipe). str/norm stores issue from
// registers, deferred one tile so barriers never drain fresh stores.
__global__ __launch_bounds__(128, 2) void anfis_main(
    const float* __restrict__ X, const float* __restrict__ A,
    const float* __restrict__ B, const float* __restrict__ C,
    float* __restrict__ out_pred, float* __restrict__ out_str,
    float* __restrict__ out_norm)
{
    __shared__ float PW[RR * DD];        // 16 KB  gaussian scale  (log2-folded)
    __shared__ float PN[RR * DD];        // 16 KB  -a*w
    __shared__ float PK[RR * DD];        // 16 KB  consequent coeffs
    __shared__ float SB[SPT * TSTR];     // 8.25 KB strengths (reduce staging)
    __shared__ float PB[SPT * TSTR];     // 8.25 KB strength*rule_out
    __shared__ float pS[SPT][8];
    __shared__ float pD[SPT][8];
    __shared__ float scl[SPT];

    const int t = threadIdx.x;           // rule id 0..127

    // ---- stage params once per block (rotated chunk layout) ----
    float bias;
    {
        const float4* av = (const float4*)(A + t * DD);
        const float4* bv = (const float4*)(B + t * DD);
        #pragma unroll
        for (int c = 0; c < 8; ++c) {
            float4 va = av[c], vb = bv[c];
            float w0 = 0.8493218003f * __builtin_amdgcn_rcpf(fmaxf(vb.x, 1e-8f));
            float w1 = 0.8493218003f * __builtin_amdgcn_rcpf(fmaxf(vb.y, 1e-8f));
            float w2 = 0.8493218003f * __builtin_amdgcn_rcpf(fmaxf(vb.z, 1e-8f));
            float w3 = 0.8493218003f * __builtin_amdgcn_rcpf(fmaxf(vb.w, 1e-8f));
            int pc = t * DD + ((c + t) & 7) * 4;
            *(float4*)&PW[pc] = make_float4(w0, w1, w2, w3);
            *(float4*)&PN[pc] = make_float4(-va.x * w0, -va.y * w1, -va.z * w2, -va.w * w3);
            *(float4*)&PK[pc] = make_float4(C[t*(DD+1)+4*c+0], C[t*(DD+1)+4*c+1],
                                            C[t*(DD+1)+4*c+2], C[t*(DD+1)+4*c+3]);
        }
        bias = C[t * (DD + 1) + DD];
    }
    __syncthreads();

    const int nblock = blockIdx.x * (SPT * TPB);
    float st_o[SPT];                     // previous tile's strengths (deferred stores)
    int n_o = 0;

    for (int tl = 0; tl < TPB; ++tl) {
        const int n0 = nblock + tl * SPT;

        // ---- deferred str/norm stores for the previous tile (stores age ~3000 cyc
        //      before the next vmcnt(0)-draining barrier) ----
        if (tl > 0) {
            float s4[SPT];
            #pragma unroll
            for (int q = 0; q < 4; ++q) {
                float4 v = *(const float4*)&scl[q * 4];   // broadcast reads
                s4[4*q+0] = v.x; s4[4*q+1] = v.y; s4[4*q+2] = v.z; s4[4*q+3] = v.w;
            }
            #pragma unroll
            for (int s = 0; s < SPT; ++s) {
                size_t base = (size_t)(n_o + s) * RR + t;  // lanes contiguous: 256 B/instr
                out_str[base]  = st_o[s];
                out_norm[base] = st_o[s] * s4[s];
            }
        }

        // ---- compute 16 samples x own rule ----
        float as_[SPT], ar_[SPT];
        #pragma unroll
        for (int s = 0; s < SPT; ++s) { as_[s] = 0.0f; ar_[s] = bias; }

        #pragma unroll
        for (int c = 0; c < 8; ++c) {
            const int pc = t * DD + ((c + t) & 7) * 4;
            float4 w4 = *(const float4*)&PW[pc];
            float4 n4 = *(const float4*)&PN[pc];
            float4 k4 = *(const float4*)&PK[pc];
            #pragma unroll
            for (int s = 0; s < SPT; ++s) {
                const float* xr = X + (size_t)(n0 + s) * DD + c * 4;  // uniform -> s_load
                float x0 = xr[0], x1 = xr[1], x2 = xr[2], x3 = xr[3];
                float t0 = fmaf(x0, w4.x, n4.x); as_[s] = fmaf(t0, t0, as_[s]); ar_[s] = fmaf(x0, k4.x, ar_[s]);
                float t1 = fmaf(x1, w4.y, n4.y); as_[s] = fmaf(t1, t1, as_[s]); ar_[s] = fmaf(x1, k4.y, ar_[s]);
                float t2 = fmaf(x2, w4.z, n4.z); as_[s] = fmaf(t2, t2, as_[s]); ar_[s] = fmaf(x2, k4.z, ar_[s]);
                float t3 = fmaf(x3, w4.w, n4.w); as_[s] = fmaf(t3, t3, as_[s]); ar_[s] = fmaf(x3, k4.w, ar_[s]);
            }
        }

        float st_[SPT];
        #pragma unroll
        for (int s = 0; s < SPT; ++s) {
            float st = __builtin_amdgcn_exp2f(-as_[s]);
            st_[s] = st;
            SB[s * TSTR + t] = st;           // bank (4s+t)%32: 2-way = free
            PB[s * TSTR + t] = st * ar_[s];
        }
        __syncthreads();

        // ---- per-sample sums over 128 rules: (s,o) split, b128 reads ----
        {
            int s = t >> 3, o = t & 7;
            const float4* sr = (const float4*)&SB[s * TSTR + o * 16];
            const float4* pr = (const float4*)&PB[s * TSTR + o * 16];
            float ss = 0.f, dd = 0.f;
            #pragma unroll
            for (int k = 0; k < 4; ++k) {
                float4 v = sr[k]; ss += (v.x + v.y) + (v.z + v.w);
                float4 p = pr[k]; dd += (p.x + p.y) + (p.z + p.w);
            }
            pS[s][o] = ss; pD[s][o] = dd;
        }
        __syncthreads();
        if (t < SPT) {
            float ss = 0.f, dd = 0.f;
            #pragma unroll
            for (int o = 0; o < 8; ++o) { ss += pS[t][o]; dd += pD[t][o]; }
            float sc = 1.0f / (ss + 1e-8f);
            out_pred[n0 + t] = dd * sc;
            scl[t] = sc;
        }
        __syncthreads();

        #pragma unroll
        for (int s = 0; s < SPT; ++s) st_o[s] = st_[s];
        n_o = n0;
    }

    // ---- epilogue: deferred stores for the last tile ----
    {
        float s4[SPT];
        #pragma unroll
        for (int q = 0; q < 4; ++q) {
            float4 v = *(const float4*)&scl[q * 4];
            s4[4*q+0] = v.x; s4[4*q+1] = v.y; s4[4*q+2] = v.z; s4[4*q+3] = v.w;
        }
        #pragma unroll
        for (int s = 0; s < SPT; ++s) {
            size_t base = (size_t)(n_o + s) * RR + t;
            out_str[base]  = st_o[s];
            out_norm[base] = st_o[s] * s4[s];
        }
    }
}

extern "C" void kernel_launch(void* const* d_in, const int* in_sizes, int n_in,
                              void* d_out, int out_size, void* d_ws, size_t ws_size,
                              hipStream_t stream) {
    const float* X = (const float*)d_in[0];
    const float* A = (const float*)d_in[1];
    const float* B = (const float*)d_in[2];
    const float* C = (const float*)d_in[3];

    float* pred = (float*)d_out;
    float* str  = pred + NS;
    float* nrm  = str + (size_t)NS * RR;

    anfis_main<<<dim3(NBLK), dim3(128), 0, stream>>>(X, A, B, C, pred, str, nrm);
}

// Round 6
// 105.846 us; speedup vs baseline: 1.9030x; 1.9030x over previous
//
#include <hip/hip_runtime.h>

#define NS 65536
#define DD 32
#define RR 128
#define SPB 16            // samples per block
#define STR 132           // padded LDS row stride (floats)

// R4 structure + inline-asm register pinning of the 97 rule params.
// Block = 128 threads = 2 waves; thread == rule. Block covers 16 samples, indexed
// only by blockIdx => X-row loads are uniform -> SGPRs (double-buffered, SMEM pipe).
// The empty asm "+v" constraints make w_/naw_/ck_/bias opaque: the compiler cannot
// sink the param loads into the sample loop (the R4 failure mode: 24 KB/wave L1
// re-reads per sample => VALUBusy capped at ~33%). Demand ~120 VGPR < 128 cap.
__global__ __launch_bounds__(128, 4) void anfis_main(
    const float* __restrict__ X, const float* __restrict__ A,
    const float* __restrict__ B, const float* __restrict__ C,
    float* __restrict__ out_pred, float* __restrict__ out_str,
    float* __restrict__ out_norm)
{
    __shared__ float SBUF[SPB * STR];   // strengths, row = sample-in-block
    __shared__ float PBUF[SPB * STR];   // strength * rule_out
    __shared__ float pS[SPB][8];
    __shared__ float pD[SPB][8];
    __shared__ float scale_lds[SPB];

    const int tid   = threadIdx.x;      // rule id
    const int nbase = blockIdx.x * SPB;

    // ---- per-thread rule params -> VGPRs (loaded once, then PINNED) ----
    float w_[DD], naw_[DD], ck_[DD], bias;
    {
        const float4* av = (const float4*)(A + tid * DD);
        const float4* bv = (const float4*)(B + tid * DD);
        #pragma unroll
        for (int i = 0; i < 8; ++i) {
            float4 va = av[i], vb = bv[i];
            float w0 = 0.8493218003f * __builtin_amdgcn_rcpf(fmaxf(vb.x, 1e-8f));
            float w1 = 0.8493218003f * __builtin_amdgcn_rcpf(fmaxf(vb.y, 1e-8f));
            float w2 = 0.8493218003f * __builtin_amdgcn_rcpf(fmaxf(vb.z, 1e-8f));
            float w3 = 0.8493218003f * __builtin_amdgcn_rcpf(fmaxf(vb.w, 1e-8f));
            w_[4*i+0] = w0; naw_[4*i+0] = -va.x * w0;
            w_[4*i+1] = w1; naw_[4*i+1] = -va.y * w1;
            w_[4*i+2] = w2; naw_[4*i+2] = -va.z * w2;
            w_[4*i+3] = w3; naw_[4*i+3] = -va.w * w3;
        }
        #pragma unroll
        for (int d = 0; d < DD; ++d) ck_[d] = C[tid * (DD + 1) + d];
        bias = C[tid * (DD + 1) + DD];
    }
    // Pin: forbid rematerialization/reload of params inside the sample loop.
    #pragma unroll
    for (int d = 0; d < DD; ++d)
        asm("" : "+v"(w_[d]), "+v"(naw_[d]), "+v"(ck_[d]));
    asm("" : "+v"(bias));

    const float* Xg = X + (size_t)nbase * DD;   // uniform base (blockIdx only)

    float xa[DD], xb[DD];   // uniform values -> SGPRs
#define LOADX(arr, jj) { _Pragma("unroll") \
    for (int i = 0; i < DD; ++i) arr[i] = Xg[(jj) * DD + i]; }

#define COMPUTE(arr, jj) { \
    float s0 = 0.f, s1 = 0.f, s2 = 0.f, s3 = 0.f; \
    float r0 = bias, r1 = 0.f, r2 = 0.f, r3 = 0.f; \
    _Pragma("unroll") \
    for (int d = 0; d < DD; d += 4) { \
        float t0 = fmaf(arr[d+0], w_[d+0], naw_[d+0]); s0 = fmaf(t0, t0, s0); r0 = fmaf(arr[d+0], ck_[d+0], r0); \
        float t1 = fmaf(arr[d+1], w_[d+1], naw_[d+1]); s1 = fmaf(t1, t1, s1); r1 = fmaf(arr[d+1], ck_[d+1], r1); \
        float t2 = fmaf(arr[d+2], w_[d+2], naw_[d+2]); s2 = fmaf(t2, t2, s2); r2 = fmaf(arr[d+2], ck_[d+2], r2); \
        float t3 = fmaf(arr[d+3], w_[d+3], naw_[d+3]); s3 = fmaf(t3, t3, s3); r3 = fmaf(arr[d+3], ck_[d+3], r3); \
    } \
    float st = __builtin_amdgcn_exp2f(-((s0 + s1) + (s2 + s3))); \
    float ro = (r0 + r1) + (r2 + r3); \
    SBUF[(jj) * STR + tid] = st; \
    PBUF[(jj) * STR + tid] = st * ro; }

    LOADX(xa, 0)
    for (int j = 0; j < SPB; j += 2) {
        LOADX(xb, j + 1)                    // prefetch j+1 while computing j
        COMPUTE(xa, j)
        if (j + 2 < SPB) LOADX(xa, j + 2)   // prefetch j+2 while computing j+1
        COMPUTE(xb, j + 1)
    }
#undef LOADX
#undef COMPUTE
    __syncthreads();

    // ---- per-sample sums over rules: 128 threads = 16 samples x 8 octants ----
    {
        int s = tid >> 3, o = tid & 7;      // 16B-group o covers 16 floats
        const float4* srow = (const float4*)&SBUF[s * STR + o * 16];
        const float4* prow = (const float4*)&PBUF[s * STR + o * 16];
        float ss = 0.f, dd = 0.f;
        #pragma unroll
        for (int k = 0; k < 4; ++k) {
            float4 v = srow[k]; ss += (v.x + v.y) + (v.z + v.w);
            float4 p = prow[k]; dd += (p.x + p.y) + (p.z + p.w);
        }
        pS[s][o] = ss; pD[s][o] = dd;
    }
    __syncthreads();
    if (tid < SPB) {
        float ss = 0.f, dd = 0.f;
        #pragma unroll
        for (int o = 0; o < 8; ++o) { ss += pS[tid][o]; dd += pD[tid][o]; }
        float sc = 1.0f / (ss + 1e-8f);
        out_pred[nbase + tid] = dd * sc;
        scale_lds[tid] = sc;
    }
    __syncthreads();

    // ---- flush strengths + normalized, float4-coalesced (1 KB contiguous per wave) ----
    #pragma unroll
    for (int it = 0; it < 4; ++it) {
        int f   = it * 128 + tid;       // float4 index over 16x32 tile
        int row = f >> 5;
        int col = f & 31;
        float4 v = *(const float4*)&SBUF[row * STR + col * 4];
        float sc = scale_lds[row];
        size_t base = ((size_t)(nbase + row)) * RR + col * 4;
        *(float4*)(out_str  + base) = v;
        *(float4*)(out_norm + base) = make_float4(v.x * sc, v.y * sc, v.z * sc, v.w * sc);
    }
}

extern "C" void kernel_launch(void* const* d_in, const int* in_sizes, int n_in,
                              void* d_out, int out_size, void* d_ws, size_t ws_size,
                              hipStream_t stream) {
    const float* X = (const float*)d_in[0];
    const float* A = (const float*)d_in[1];
    const float* B = (const float*)d_in[2];
    const float* C = (const float*)d_in[3];

    float* pred = (float*)d_out;
    float* str  = pred + NS;
    float* nrm  = str + (size_t)NS * RR;

    anfis_main<<<dim3(NS / SPB), dim3(128), 0, stream>>>(X, A, B, C, pred, str, nrm);
}